// Round 7
// baseline (3252.898 us; speedup 1.0000x reference)
//
#include <hip/hip_runtime.h>

#define Bb 256
#define Tt 256
#define Dd 64
#define Hh 512
#define BH (Bb*Hh)
#define S1 4                       // h1 slots (L0 run-ahead slack)

typedef _Float16 half8 __attribute__((ext_vector_type(8)));
typedef float floatx4 __attribute__((ext_vector_type(4)));
typedef unsigned long long u64x2 __attribute__((ext_vector_type(2)));

__device__ __forceinline__ float sigm(float x) { return 1.0f/(1.0f + __expf(-x)); }
__device__ __forceinline__ float tanh_(float x) {
  if (x >  15.0f) return  1.0f;
  if (x < -15.0f) return -1.0f;
  float e = __expf(2.0f*x);
  return (e - 1.0f)/(e + 1.0f);
}

// Device(agent)-scope coherent accesses: coherence point = shared LLC (Infinity
// Cache), NOT DRAM. Compiler-managed waitcnts/spills; no cache-wide fences.
__device__ __forceinline__ half8 ld_h8(const _Float16* p) {
  u64x2 t;
  t.x = __hip_atomic_load((const unsigned long long*)p,       __ATOMIC_RELAXED, __HIP_MEMORY_SCOPE_AGENT);
  t.y = __hip_atomic_load(((const unsigned long long*)p) + 1, __ATOMIC_RELAXED, __HIP_MEMORY_SCOPE_AGENT);
  return __builtin_bit_cast(half8, t);
}
__device__ __forceinline__ void st_u64(_Float16* p, unsigned long long v) {
  __hip_atomic_store((unsigned long long*)p, v, __ATOMIC_RELAXED, __HIP_MEMORY_SCOPE_AGENT);
}
__device__ __forceinline__ unsigned ld_flag(const unsigned* p) {
  return __hip_atomic_load(p, __ATOMIC_RELAXED, __HIP_MEMORY_SCOPE_AGENT);
}
__device__ __forceinline__ void st_flag(unsigned* p, unsigned v) {
  __hip_atomic_store(p, v, __ATOMIC_RELAXED, __HIP_MEMORY_SCOPE_AGENT);
}

// ws layout: xf16[T*B*D] | h1[S1*BH] | h2[2*BH] | flags[512]
// flags[g*32 + cgi]: epoch flag of block (group g, col-group cgi)
__global__ void init_kernel(const float* __restrict__ x,
                            _Float16* __restrict__ xf16,
                            _Float16* __restrict__ hz,
                            unsigned* __restrict__ flags) {
  const int j0 = blockIdx.x*blockDim.x + threadIdx.x;
  if (j0 < 512) flags[j0] = 0u;
  const int NX = Bb*Tt*Dd;          // 4194304
  const int NZ = (S1+2)*BH;         // h1 x S1 + h2 x2
  for (int j = j0; j < NX + NZ; j += gridDim.x*blockDim.x) {
    if (j < NX) {
      int t = j >> 14, r = j & 16383;
      int b = r >> 6, d = r & 63;
      xf16[j] = (_Float16)x[(b << 14) + (t << 6) + d];
    } else {
      hz[j - NX] = (_Float16)0.0f;
    }
  }
}

__global__ void __launch_bounds__(256, 1)
lstm_fused(const _Float16* __restrict__ xf16,
           _Float16* __restrict__ hbufs,      // h1[S1 x BH] then h2[2 x BH]
           unsigned* __restrict__ flags,
           const float* __restrict__ Wih0, const float* __restrict__ Whh0,
           const float* __restrict__ bih0, const float* __restrict__ bhh0,
           const float* __restrict__ Wih1, const float* __restrict__ Whh1,
           const float* __restrict__ bih1, const float* __restrict__ bhh1,
           const float* __restrict__ fcw,  const float* __restrict__ fcb,
           float* __restrict__ out)
{
  // LDS: W fragment groups g=(ks*4+bt), 512 halfs each; LANE-MAJOR within group:
  // lane l=(kg*16+n15) owns halfs [g*512 + l*8 .. +7] -> wave ds_read_b128 covers
  // a contiguous 1KiB: all 32 banks, conflict-free.
  // 65536 halfs W + 4 waves x 256 halfs h-store staging = 133120 B total.
  extern __shared__ _Float16 lds[];

  const int tid = threadIdx.x;
  const int bid = blockIdx.x;
  const int grp = bid & 7;            // (layer,rgi) group
  const int lb  = grp >> 2;           // layer
  const int rgi = grp & 3;            // batch row-group (64 rows)
  const int cgi = bid >> 3;           // 0..31 col-group (16 h-cols)
  const int hc0 = cgi * 16;
  const int r0  = rgi * 64;

  unsigned* const myflag = flags + grp*32 + cgi;

  _Float16* const h1buf = hbufs;            // S1 slots
  _Float16* const h2buf = hbufs + S1*BH;    // 2 slots

  // ---- preload W slice (fp32 -> fp16) into lane-major fragment LDS ----
  {
    const float* Whh = lb ? Whh1 : Whh0;
    const float* Wih = lb ? Wih1 : Wih0;
    const int Kin = lb ? Hh : Dd;
    const int KT  = Hh + Kin;                 // k_total range
    for (int idx = tid; idx < 64*KT; idx += 256) {
      const int gr = idx / KT;                // 64 gate-rows handled by this block
      const int k  = idx - gr*KT;
      const int bt = gr >> 4, s = gr & 15;
      const int gate = (bt & 1)*2 + (s >> 3);           // 0=i,1=f,2=g,3=o
      const int hcc  = (bt >> 1)*8 + (s & 7);
      const int wrow = gate*Hh + hc0 + hcc;
      const float v = (k < Hh) ? Whh[(size_t)wrow*Hh + k]
                               : Wih[(size_t)wrow*Kin + (k - Hh)];
      // group = (k>>5)*4 + bt; lane = ((k>>3)&3)*16 + s; elem = k&7
      const int li = (((k >> 5)*4 + bt) << 9) + ((((k >> 3) & 3)*16 + s) << 3) + (k & 7);
      lds[li] = (_Float16)v;
    }
  }
  __syncthreads();

  // lane geometry: wave tile = 16 rows x all 64 gate-cols (4 b-tiles)
  const int w    = tid >> 6;
  const int lane = tid & 63;
  const int kg   = lane >> 4;
  const int n15  = lane & 15;
  const bool lo  = (n15 < 8);
  const int rowb = r0 + w*16;              // wave's rows: rowb..rowb+15 (A row = rowb+n15)

  const _Float16* const bfrag = lds + (lane << 3);           // + (ks*4+bt)*512
  _Float16* const stage = lds + 65536 + w*256;               // 16 rows x 16 cols

  const float* bi = lb ? bih1 : bih0;
  const float* bh = lb ? bhh1 : bhh0;
  float biasA[2], biasB[2];                // per hcol-octet: A = i|f, B = g|o
  #pragma unroll
  for (int o = 0; o < 2; ++o) {
    const int hc = hc0 + o*8 + (n15 & 7);
    biasA[o] = lo ? (bi[hc]      + bh[hc])      : (bi[512+hc]  + bh[512+hc]);
    biasB[o] = lo ? (bi[1024+hc] + bh[1024+hc]) : (bi[1536+hc] + bh[1536+hc]);
  }

  float cst[2][4] = {{0.f,0.f,0.f,0.f},{0.f,0.f,0.f,0.f}};

  for (int i = 0; i <= Tt; ++i) {
    const bool active = lb ? (i >= 1) : (i < Tt);
    if (active) {
      // ---- acquire: poll epoch flags ----
      // own group >= i; cross: L1 needs prog0 >= i, L0 needs prog1 >= i-(S1-2)
      if (tid < 64) {
        const int gsel = (tid < 32) ? grp : (grp ^ 4);
        unsigned tgt;
        if (tid < 32)      tgt = (unsigned)i;
        else if (lb)       tgt = (unsigned)i;
        else               tgt = (i >= S1) ? (unsigned)(i - (S1 - 2)) : 0u;
        const unsigned* fp = flags + gsel*32 + (tid & 31);
        while (!__all((int)(ld_flag(fp) >= tgt)))
          __builtin_amdgcn_s_sleep(1);
      }
      __syncthreads();
      asm volatile("" ::: "memory");            // no hoisting of h loads above the poll
      __builtin_amdgcn_sched_barrier(0);

      const _Float16* hprev; _Float16* hcur; const _Float16* src2;
      if (lb) {
        hprev = h2buf + (size_t)((i+1)&1)*BH;
        hcur  = h2buf + (size_t)(i&1)*BH;
        src2  = h1buf + (size_t)((i+S1-1)%S1)*BH;   // layer0 timestep i-1
      } else {
        hprev = h1buf + (size_t)((i+S1-1)%S1)*BH;   // own timestep i-1
        hcur  = h1buf + (size_t)(i%S1)*BH;
        src2  = xf16 + (size_t)i*(Bb*Dd);
      }

      floatx4 acc[4] = {};   // bt: 0=i/f oct0, 1=g/o oct0, 2=i/f oct1, 3=g/o oct1
      const _Float16* const arow = hprev + (size_t)(rowb + n15)*Hh + 8*kg;

      if (lb) {
        half8 a1[16], a2[16];
        const _Float16* const crow = src2 + (size_t)(rowb + n15)*Hh + 8*kg;
        #pragma unroll
        for (int ks = 0; ks < 16; ++ks) a1[ks] = ld_h8(arow + 32*ks);
        #pragma unroll
        for (int ks = 0; ks < 16; ++ks) a2[ks] = ld_h8(crow + 32*ks);
        #pragma unroll
        for (int ks = 0; ks < 16; ++ks)
          #pragma unroll
          for (int bt = 0; bt < 4; ++bt)
            acc[bt] = __builtin_amdgcn_mfma_f32_16x16x32_f16(
                        a1[ks], *(const half8*)(bfrag + ((ks*4 + bt) << 9)), acc[bt], 0,0,0);
        #pragma unroll
        for (int ks = 0; ks < 16; ++ks)
          #pragma unroll
          for (int bt = 0; bt < 4; ++bt)
            acc[bt] = __builtin_amdgcn_mfma_f32_16x16x32_f16(
                        a2[ks], *(const half8*)(bfrag + (((16+ks)*4 + bt) << 9)), acc[bt], 0,0,0);
      } else {
        half8 a1[16], a2[2];
        const _Float16* const crow = src2 + (size_t)(rowb + n15)*Dd + 8*kg;
        #pragma unroll
        for (int ks = 0; ks < 16; ++ks) a1[ks] = ld_h8(arow + 32*ks);
        #pragma unroll
        for (int ks = 0; ks < 2; ++ks)  a2[ks] = *(const half8*)(crow + 32*ks);  // x: cached
        #pragma unroll
        for (int ks = 0; ks < 16; ++ks)
          #pragma unroll
          for (int bt = 0; bt < 4; ++bt)
            acc[bt] = __builtin_amdgcn_mfma_f32_16x16x32_f16(
                        a1[ks], *(const half8*)(bfrag + ((ks*4 + bt) << 9)), acc[bt], 0,0,0);
        #pragma unroll
        for (int ks = 0; ks < 2; ++ks)
          #pragma unroll
          for (int bt = 0; bt < 4; ++bt)
            acc[bt] = __builtin_amdgcn_mfma_f32_16x16x32_f16(
                        a2[ks], *(const half8*)(bfrag + (((16+ks)*4 + bt) << 9)), acc[bt], 0,0,0);
      }

      // pointwise: lanes n15<8 hold i,g; n15>=8 hold f,o (pair via lane^8); stage h in LDS
      #pragma unroll
      for (int o = 0; o < 2; ++o) {
        #pragma unroll
        for (int rr = 0; rr < 4; ++rr) {
          const float pA = acc[2*o][rr]   + biasA[o];
          const float pB = acc[2*o+1][rr] + biasB[o];
          const float v1 = sigm(pA);                    // sig(i) | sig(f)
          const float v2 = lo ? tanh_(pB) : sigm(pB);   // tanh(g) | sig(o)
          const float fs  = __shfl_xor(v1, 8, 64);
          const float os_ = __shfl_xor(v2, 8, 64);
          if (lo) {
            const float c = fs * cst[o][rr] + v1 * v2;
            cst[o][rr] = c;
            const float hval = os_ * tanh_(c);
            stage[(kg*4 + rr)*16 + o*8 + (n15 & 7)] = (_Float16)hval;
          }
        }
      }
      // wave-local staging flush -> one coalesced 8B device-scope store per lane
      asm volatile("s_waitcnt lgkmcnt(0)" ::: "memory");
      __builtin_amdgcn_sched_barrier(0);
      const unsigned long long pk = *(const unsigned long long*)(stage + (lane << 2));
      st_u64(hcur + (size_t)(rowb + (lane >> 2))*Hh + hc0 + (lane & 3)*4, pk);
    }

    // ---- release: drain stores to LLC, block sync, publish epoch ----
    asm volatile("s_waitcnt vmcnt(0)" ::: "memory");
    __syncthreads();
    if (tid == 0) st_flag(myflag, (unsigned)(i + 1));
  }

  // FC: out[b] = h2_final[b,:] . fcw + fcb   (layer1 last writes at i=256 -> slot 0)
  if (bid == 0) {
    if (tid < 64) {
      const unsigned* f1 = flags + (4 + (tid >> 5))*32 + (tid & 31);  // groups 4,5
      const unsigned* f2 = f1 + 64;                                    // groups 6,7
      while (true) {
        int ok = (ld_flag(f1) > (unsigned)Tt) & (ld_flag(f2) > (unsigned)Tt);
        if (__all(ok)) break;
        __builtin_amdgcn_s_sleep(1);
      }
    }
    __syncthreads();
    asm volatile("" ::: "memory");
    const _Float16* h2 = h2buf;
    float acc = fcb[0];
    for (int c = 0; c < 4; ++c) {
      half8 v[16];
      #pragma unroll
      for (int j = 0; j < 16; ++j)
        v[j] = ld_h8(h2 + (size_t)tid*Hh + c*128 + j*8);
      #pragma unroll
      for (int j = 0; j < 16; ++j)
        #pragma unroll
        for (int e = 0; e < 8; ++e)
          acc += (float)v[j][e] * fcw[c*128 + j*8 + e];
    }
    out[tid] = acc;
  }
}

extern "C" void kernel_launch(void* const* d_in, const int* in_sizes, int n_in,
                              void* d_out, int out_size, void* d_ws, size_t ws_size,
                              hipStream_t stream) {
  const float* x    = (const float*)d_in[0];
  const float* Wih0 = (const float*)d_in[1];
  const float* Whh0 = (const float*)d_in[2];
  const float* bih0 = (const float*)d_in[3];
  const float* bhh0 = (const float*)d_in[4];
  const float* Wih1 = (const float*)d_in[5];
  const float* Whh1 = (const float*)d_in[6];
  const float* bih1 = (const float*)d_in[7];
  const float* bhh1 = (const float*)d_in[8];
  const float* fcw  = (const float*)d_in[9];
  const float* fcb  = (const float*)d_in[10];
  float* out = (float*)d_out;

  _Float16* xf16  = (_Float16*)d_ws;                         // 8,388,608 B
  _Float16* hbufs = xf16 + (size_t)Bb*Tt*Dd;                 // (S1+2)*BH halfs
  unsigned* flags = (unsigned*)(hbufs + (size_t)(S1+2)*BH);  // 2 KiB

  hipFuncSetAttribute((const void*)lstm_fused,
                      hipFuncAttributeMaxDynamicSharedMemorySize, 133120);

  hipLaunchKernelGGL(init_kernel, dim3(1024), dim3(256), 0, stream, x, xf16, hbufs, flags);

  hipLaunchKernelGGL(lstm_fused, dim3(256), dim3(256), 133120, stream,
                     (const _Float16*)xf16, hbufs, flags,
                     Wih0, Whh0, bih0, bhh0, Wih1, Whh1, bih1, bhh1, fcw, fcb, out);
}